// Round 1
// baseline (1752.077 us; speedup 1.0000x reference)
//
#include <hip/hip_runtime.h>
#include <hip/hip_bf16.h>
#include <cstdint>
#include <cstddef>

typedef float  f32x4  __attribute__((ext_vector_type(4)));
typedef __bf16 bf16x8 __attribute__((ext_vector_type(8)));

#define DEV __device__ __forceinline__

DEV float gelu_f(float x){ return 0.5f * x * (1.0f + erff(x * 0.70710678118654752f)); }

// ---------------- workspace layout (bytes) ----------------
static constexpr size_t OFF_FX     = 0;                       // fx fp32 [16384,512]   33554432
static constexpr size_t OFF_H      = 33554432;                // h bf16 [16384,512]    16777216
static constexpr size_t OFF_REGA   = 50331648;                // 67108864 region (fx_mid|logits|sw, reused by mlph/h1)
static constexpr size_t OFF_FXMID  = OFF_REGA;                // fp32 [16384,512]      33554432
static constexpr size_t OFF_LOGITS = OFF_REGA + 33554432;     // fp32 [16384,256]      16777216
static constexpr size_t OFF_SW     = OFF_REGA + 50331648;     // fp32 [16,8192,32]     16777216
static constexpr size_t OFF_MLPH   = OFF_REGA;                // bf16 [16384,2048]     67108864 (after sw dead)
static constexpr size_t OFF_H1     = OFF_REGA;                // bf16 [16384,1024]     33554432 (preprocess only)
static constexpr size_t OFF_OUTB   = OFF_REGA + 67108864;     // bf16 [16384,512]      16777216
static constexpr size_t OFF_PT     = OFF_OUTB + 16777216;     // fp32 [16,16,32,64]    2097152
static constexpr size_t OFF_PTM    = OFF_PT + 2097152;        // fp32 [16,16,32]       32768
static constexpr size_t OFF_TOKN   = OFF_PTM + 32768;         // fp32 [16,32,64]       131072
static constexpr size_t OFF_OT     = OFF_TOKN + 131072;       // fp32 [16,32,64]       131072
static constexpr size_t OFF_WT     = OFF_OT + 131072;         // bf16 transposed weights 23068672
static constexpr size_t OFF_BIAS   = OFF_WT + 23068672;       // blog[4][256] f32 + bpre2p[512] f32
// total ~159.7 MB

// ---------------- weight prep ----------------
// transpose fp32 W[K][N] -> bf16 Wt[N][K]; grid (K/64, N/64), block 256
__global__ __launch_bounds__(256) void wtrans_k(const float* __restrict__ W, __bf16* __restrict__ Wt, int K, int N)
{
  __shared__ float tile[64][65];
  int t = threadIdx.x;
  int k0 = blockIdx.x * 64, n0 = blockIdx.y * 64;
  #pragma unroll
  for (int i = 0; i < 16; i++){
    int e = t + 256*i; int kk = e >> 6, nn = e & 63;
    tile[kk][nn] = W[(size_t)(k0+kk)*N + n0+nn];
  }
  __syncthreads();
  #pragma unroll
  for (int i = 0; i < 16; i++){
    int e = t + 256*i; int nn = e >> 6, kk = e & 63;
    Wt[(size_t)(n0+nn)*K + k0+kk] = (__bf16)tile[kk][nn];
  }
}

// Wxs_t[hg][c] = (sum_d Wx[c][h*64+d]*Wslice[d][g]) / temp[h]  (bf16, transposed)
// blog[hg] = (sum_d bx[h*64+d]*Wslice[d][g] + bslice[g]) / temp[h]
// grid 256 (hg), block 128
__global__ __launch_bounds__(128) void prep_wxs_k(const float* __restrict__ Wx_l, const float* __restrict__ Wsl,
                                                  const float* __restrict__ bx_l, const float* __restrict__ bsl,
                                                  const float* __restrict__ temp_l,
                                                  __bf16* __restrict__ Wxs_t, float* __restrict__ blog)
{
  __shared__ float wsc[64];
  int hg = blockIdx.x; int h = hg >> 5, g = hg & 31;
  int t = threadIdx.x;
  if (t < 64) wsc[t] = Wsl[t*32 + g];
  __syncthreads();
  float invt = 1.0f / temp_l[h];
  #pragma unroll
  for (int cc = 0; cc < 4; cc++){
    int c = t + cc*128;
    float a = 0.f;
    for (int d = 0; d < 64; d++) a += Wx_l[(size_t)c*512 + h*64 + d] * wsc[d];
    Wxs_t[(size_t)hg*512 + c] = (__bf16)(a * invt);
  }
  if (t == 0){
    float a = 0.f;
    for (int d = 0; d < 64; d++) a += bx_l[h*64 + d] * wsc[d];
    blog[hg] = (a + bsl[g]) * invt;
  }
}

__global__ __launch_bounds__(256) void addbias_k(const float* __restrict__ a, const float* __restrict__ b,
                                                 float* __restrict__ o)
{
  int i = blockIdx.x*256 + threadIdx.x;
  if (i < 512) o[i] = a[i] + b[i];
}

// ---------------- preprocess stage 1 ----------------
// h1[m][j] = bf16(gelu( b_pre1[j] + sum_c x[m][c]*W_pre1[c][j] )), x = [emb(3) | fun(7)]
__global__ __launch_bounds__(256) void preproc1_k(const float* __restrict__ fun, const float* __restrict__ emb,
                                                  const float* __restrict__ W1, const float* __restrict__ b1,
                                                  __bf16* __restrict__ h1)
{
  int gid = blockIdx.x*256 + threadIdx.x;   // 16384*1024
  int m = gid >> 10, j = gid & 1023;
  float acc = b1[j];
  const float* er = emb + (size_t)m*3;
  const float* fr = fun + (size_t)m*7;
  #pragma unroll
  for (int c = 0; c < 3; c++) acc += er[c] * W1[c*1024 + j];
  #pragma unroll
  for (int c = 0; c < 7; c++) acc += fr[c] * W1[(3+c)*1024 + j];
  h1[gid] = (__bf16)gelu_f(acc);
}

// ---------------- MFMA GEMM: D[M,N] = A[M,K](bf16) @ Bt[N,K]^T(bf16) + epilogue ----------------
// EPI 0: out fp32 = acc + bias
// EPI 1: out bf16 = gelu(acc + bias)
// EPI 2: out fp32 = acc + bias + res
// grid (M/128, N/128), block 256 (4 waves, 2x2 of 64x64; each wave 4x4 MFMA 16x16x32 tiles)
template<int EPI>
__global__ __launch_bounds__(256) void gemm_bt(const __bf16* __restrict__ A, const __bf16* __restrict__ Bt,
                                               const float* __restrict__ bias, const float* __restrict__ res,
                                               void* __restrict__ outp, int M, int N, int K)
{
  __shared__ bf16x8 ldsA[8][64];   // fragment-order: [subtile][lane] -> A[sub*16+(l&15)][(l>>4)*8+j]
  __shared__ bf16x8 ldsB[8][64];
  const int tid = threadIdx.x;
  const int w = tid >> 6, lane = tid & 63;
  const int lm = lane & 15, lq = lane >> 4;
  const int m0 = blockIdx.x * 128, n0 = blockIdx.y * 128;
  const int wm = (w >> 1) * 64, wn = (w & 1) * 64;

  f32x4 acc[4][4] = {};

  const int s0 = w*2, s1 = w*2 + 1;      // subtiles staged by this wave
  const __bf16* Ag0 = A  + (size_t)(m0 + s0*16 + lm)*K + lq*8;
  const __bf16* Ag1 = A  + (size_t)(m0 + s1*16 + lm)*K + lq*8;
  const __bf16* Bg0 = Bt + (size_t)(n0 + s0*16 + lm)*K + lq*8;
  const __bf16* Bg1 = Bt + (size_t)(n0 + s1*16 + lm)*K + lq*8;

  for (int k0 = 0; k0 < K; k0 += 32){
    bf16x8 a0 = *(const bf16x8*)Ag0; Ag0 += 32;
    bf16x8 a1 = *(const bf16x8*)Ag1; Ag1 += 32;
    bf16x8 b0 = *(const bf16x8*)Bg0; Bg0 += 32;
    bf16x8 b1 = *(const bf16x8*)Bg1; Bg1 += 32;
    __syncthreads();
    ldsA[s0][lane] = a0;
    ldsA[s1][lane] = a1;
    ldsB[s0][lane] = b0;
    ldsB[s1][lane] = b1;
    __syncthreads();
    bf16x8 af[4], bfr[4];
    #pragma unroll
    for (int i = 0; i < 4; i++) af[i]  = ldsA[(wm>>4) + i][lane];
    #pragma unroll
    for (int j = 0; j < 4; j++) bfr[j] = ldsB[(wn>>4) + j][lane];
    #pragma unroll
    for (int i = 0; i < 4; i++)
      #pragma unroll
      for (int j = 0; j < 4; j++)
        acc[i][j] = __builtin_amdgcn_mfma_f32_16x16x32_bf16(af[i], bfr[j], acc[i][j], 0, 0, 0);
  }

  #pragma unroll
  for (int i = 0; i < 4; i++){
    int row0 = m0 + wm + i*16 + lq*4;
    #pragma unroll
    for (int j = 0; j < 4; j++){
      int col = n0 + wn + j*16 + lm;
      float bv = bias[col];
      #pragma unroll
      for (int r = 0; r < 4; r++){
        size_t idx = (size_t)(row0 + r)*N + col;
        float v = acc[i][j][r] + bv;
        if (EPI == 2) v += res[idx];
        if (EPI == 1) ((__bf16*)outp)[idx] = (__bf16)gelu_f(v);
        else          ((float*)outp)[idx]  = v;
      }
    }
  }
}

// ---------------- LayerNorm (512 cols), fp32 in -> bf16 out; 1 wave/row ----------------
__global__ __launch_bounds__(256) void ln_k(const float* __restrict__ x, const float* __restrict__ g,
                                            const float* __restrict__ b, __bf16* __restrict__ out)
{
  int w = threadIdx.x >> 6, lane = threadIdx.x & 63;
  int row = blockIdx.x*4 + w;
  const float* xr = x + (size_t)row*512 + lane*8;
  float v[8];
  *(f32x4*)&v[0] = *(const f32x4*)xr;
  *(f32x4*)&v[4] = *(const f32x4*)(xr + 4);
  float s = 0.f, sq = 0.f;
  #pragma unroll
  for (int e = 0; e < 8; e++){ s += v[e]; sq += v[e]*v[e]; }
  #pragma unroll
  for (int off = 32; off; off >>= 1){ s += __shfl_xor(s, off); sq += __shfl_xor(sq, off); }
  float mean = s * (1.f/512.f);
  float var  = sq * (1.f/512.f) - mean*mean;
  float rstd = rsqrtf(var + 1e-5f);
  float gv[8], bv[8];
  *(f32x4*)&gv[0] = *(const f32x4*)(g + lane*8);
  *(f32x4*)&gv[4] = *(const f32x4*)(g + lane*8 + 4);
  *(f32x4*)&bv[0] = *(const f32x4*)(b + lane*8);
  *(f32x4*)&bv[4] = *(const f32x4*)(b + lane*8 + 4);
  __bf16* op = out + (size_t)row*512 + lane*8;
  #pragma unroll
  for (int e = 0; e < 8; e++) op[e] = (__bf16)((v[e]-mean)*rstd*gv[e] + bv[e]);
}

// ---------------- slice softmax: logits[m][h*32+g] -> sw[(b*8+h)][n][g] ----------------
__global__ __launch_bounds__(256) void softmax_k(const float* __restrict__ logits, float* __restrict__ sw)
{
  int gid = blockIdx.x*256 + threadIdx.x;   // 16384*8
  int m = gid >> 3, h = gid & 7;
  const float* lp = logits + (size_t)m*256 + h*32;
  float x[32];
  #pragma unroll
  for (int i = 0; i < 8; i++) *(f32x4*)&x[i*4] = *(const f32x4*)(lp + i*4);
  float mx = x[0];
  #pragma unroll
  for (int i = 1; i < 32; i++) mx = fmaxf(mx, x[i]);
  float s = 0.f;
  #pragma unroll
  for (int i = 0; i < 32; i++){ x[i] = expf(x[i]-mx); s += x[i]; }
  float inv = 1.f / s;
  int b = m >> 13, n = m & 8191;
  float* op = sw + ((size_t)(b*8 + h)*8192 + n)*32;
  #pragma unroll
  for (int i = 0; i < 8; i++){
    f32x4 t = *(f32x4*)&x[i*4];
    t *= inv;
    *(f32x4*)(op + i*4) = t;
  }
}

// ---------------- token partial: per (chunk, bh) accumulate sw^T @ fx_mid over 512 n ----------------
__global__ __launch_bounds__(256) void token_part_k(const float* __restrict__ fx_mid, const float* __restrict__ sw,
                                                    float* __restrict__ pt, float* __restrict__ ptm)
{
  __shared__ float fxl[32][64];
  __shared__ float swl[32][32];
  int t = threadIdx.x;
  int chunk = blockIdx.x, bh = blockIdx.y;
  int b = bh >> 3, h = bh & 7;
  int d = t & 63, gg = (t >> 6) * 8;
  float acc[8] = {0,0,0,0,0,0,0,0};
  float macc = 0.f;
  for (int s = 0; s < 16; s++){
    int nbase = chunk*512 + s*32;
    __syncthreads();
    #pragma unroll
    for (int i = 0; i < 2; i++){
      int e = t + 256*i; int rv = e >> 4, c4 = e & 15;
      *(f32x4*)&fxl[rv][c4*4] = *(const f32x4*)&fx_mid[(((size_t)b*8192 + nbase + rv)*8 + h)*64 + c4*4];
    }
    { int rv = t >> 3, c4 = t & 7;
      *(f32x4*)&swl[rv][c4*4] = *(const f32x4*)&sw[((size_t)bh*8192 + nbase + rv)*32 + c4*4]; }
    __syncthreads();
    for (int nn = 0; nn < 32; nn++){
      float f = fxl[nn][d];
      #pragma unroll
      for (int jj = 0; jj < 8; jj++) acc[jj] += f * swl[nn][gg+jj];
    }
    if (t < 32){ for (int nn = 0; nn < 32; nn++) macc += swl[nn][t]; }
  }
  int cb = chunk*16 + bh;
  #pragma unroll
  for (int jj = 0; jj < 8; jj++)
    pt[((size_t)cb*32 + gg + jj)*64 + d] = acc[jj];
  if (t < 32) ptm[cb*32 + t] = macc;
}

// ---------------- token reduce: sum chunks, divide by (mass+1e-5) ----------------
__global__ __launch_bounds__(256) void token_reduce_k(const float* __restrict__ pt, const float* __restrict__ ptm,
                                                      float* __restrict__ token)
{
  __shared__ float ml[32];
  int t = threadIdx.x, bh = blockIdx.x;
  if (t < 32){
    float s = 0.f;
    for (int c = 0; c < 16; c++) s += ptm[(c*16 + bh)*32 + t];
    ml[t] = s + 1e-5f;
  }
  __syncthreads();
  #pragma unroll
  for (int i = 0; i < 8; i++){
    int e = t + 256*i; int g = e >> 6, d = e & 63;
    float s = 0.f;
    for (int c = 0; c < 16; c++) s += pt[((size_t)(c*16 + bh)*32 + g)*64 + d];
    token[((size_t)bh*32 + g)*64 + d] = s / ml[g];
  }
}

// ---------------- tiny attention over 32 tokens per (b,h) ----------------
__global__ __launch_bounds__(256) void attn_k(const float* __restrict__ token, const float* __restrict__ Wq,
                                              const float* __restrict__ Wk, const float* __restrict__ Wv,
                                              float* __restrict__ ot)
{
  __shared__ float tok[32][64];
  __shared__ float qq[32][65], kk2[32][65], vv[32][65];
  __shared__ float at[32][33];
  int t = threadIdx.x, bh = blockIdx.x;
  #pragma unroll
  for (int i = 0; i < 8; i++){
    int e = t + 256*i;
    tok[e>>6][e&63] = token[(size_t)bh*2048 + e];
  }
  __syncthreads();
  #pragma unroll
  for (int i = 0; i < 8; i++){
    int e = t + 256*i; int g = e >> 6, j = e & 63;
    float aq = 0.f, ak = 0.f, av = 0.f;
    for (int d = 0; d < 64; d++){
      float tv = tok[g][d];
      aq += tv * Wq[d*64 + j];
      ak += tv * Wk[d*64 + j];
      av += tv * Wv[d*64 + j];
    }
    qq[g][j] = aq; kk2[g][j] = ak; vv[g][j] = av;
  }
  __syncthreads();
  #pragma unroll
  for (int i = 0; i < 4; i++){
    int e = t + 256*i; int g = e >> 5, j2 = e & 31;
    float s2 = 0.f;
    for (int d = 0; d < 64; d++) s2 += qq[g][d] * kk2[j2][d];
    at[g][j2] = s2 * 0.125f;
  }
  __syncthreads();
  if (t < 32){
    float mx = at[t][0];
    for (int j = 1; j < 32; j++) mx = fmaxf(mx, at[t][j]);
    float ss = 0.f;
    for (int j = 0; j < 32; j++){ float e2 = expf(at[t][j]-mx); at[t][j] = e2; ss += e2; }
    float inv = 1.f / ss;
    for (int j = 0; j < 32; j++) at[t][j] *= inv;
  }
  __syncthreads();
  #pragma unroll
  for (int i = 0; i < 8; i++){
    int e = t + 256*i; int g = e >> 6, d = e & 63;
    float s3 = 0.f;
    for (int j = 0; j < 32; j++) s3 += at[g][j] * vv[j][d];
    ot[(size_t)bh*2048 + e] = s3;
  }
}

// ---------------- de-slice: out[b,n,h*64+d] = sum_g ot[bh][g][d]*sw[bh][n][g] (bf16 out) ----------------
__global__ __launch_bounds__(256) void deslice_k(const float* __restrict__ ot, const float* __restrict__ sw,
                                                 __bf16* __restrict__ outb)
{
  __shared__ float otl[32][64];
  __shared__ float swl[4][33];
  int t = threadIdx.x;
  int chunk = blockIdx.x, bh = blockIdx.y;
  int b = bh >> 3, h = bh & 7;
  #pragma unroll
  for (int i = 0; i < 8; i++){
    int e = t + 256*i;
    otl[e>>6][e&63] = ot[(size_t)bh*2048 + e];
  }
  int n0 = chunk*128;
  int nsub = t >> 6, d = t & 63;
  for (int s = 0; s < 32; s++){
    __syncthreads();
    if (t < 128) swl[t>>5][t&31] = sw[((size_t)bh*8192 + n0 + s*4 + (t>>5))*32 + (t&31)];
    __syncthreads();
    float a2 = 0.f;
    #pragma unroll
    for (int g = 0; g < 32; g++) a2 += otl[g][d] * swl[nsub][g];
    int n = n0 + s*4 + nsub;
    outb[((size_t)(b*8192 + n))*512 + h*64 + d] = (__bf16)a2;
  }
}

// ---------------- final head: LN + [512,4] matmul; 1 wave/row ----------------
__global__ __launch_bounds__(256) void head_k(const float* __restrict__ x, const float* __restrict__ g,
                                              const float* __restrict__ b, const float* __restrict__ Wout,
                                              const float* __restrict__ bout, float* __restrict__ out)
{
  int w = threadIdx.x >> 6, lane = threadIdx.x & 63;
  int row = blockIdx.x*4 + w;
  const float* xr = x + (size_t)row*512 + lane*8;
  float v[8];
  *(f32x4*)&v[0] = *(const f32x4*)xr;
  *(f32x4*)&v[4] = *(const f32x4*)(xr + 4);
  float s = 0.f, sq = 0.f;
  #pragma unroll
  for (int e = 0; e < 8; e++){ s += v[e]; sq += v[e]*v[e]; }
  #pragma unroll
  for (int off = 32; off; off >>= 1){ s += __shfl_xor(s, off); sq += __shfl_xor(sq, off); }
  float mean = s * (1.f/512.f);
  float rstd = rsqrtf(sq * (1.f/512.f) - mean*mean + 1e-5f);
  float o[4] = {0,0,0,0};
  #pragma unroll
  for (int e = 0; e < 8; e++){
    int c = lane*8 + e;
    float yn = (v[e]-mean)*rstd*g[c] + b[c];
    const float* wr = Wout + (size_t)c*4;
    o[0] += yn*wr[0]; o[1] += yn*wr[1]; o[2] += yn*wr[2]; o[3] += yn*wr[3];
  }
  #pragma unroll
  for (int off = 32; off; off >>= 1){
    #pragma unroll
    for (int j = 0; j < 4; j++) o[j] += __shfl_xor(o[j], off);
  }
  if (lane == 0){
    #pragma unroll
    for (int j = 0; j < 4; j++) out[(size_t)row*4 + j] = o[j] + bout[j];
  }
}

extern "C" void kernel_launch(void* const* d_in, const int* in_sizes, int n_in,
                              void* d_out, int out_size, void* d_ws, size_t ws_size,
                              hipStream_t stream)
{
  const float* fun    = (const float*)d_in[0];
  const float* emb    = (const float*)d_in[1];
  const float* W_pre1 = (const float*)d_in[2];
  const float* b_pre1 = (const float*)d_in[3];
  const float* W_pre2 = (const float*)d_in[4];
  const float* b_pre2 = (const float*)d_in[5];
  const float* placeholder = (const float*)d_in[6];
  const float* ln1_g  = (const float*)d_in[7];
  const float* ln1_b  = (const float*)d_in[8];
  const float* Wfx    = (const float*)d_in[9];
  const float* bfx    = (const float*)d_in[10];
  const float* Wx     = (const float*)d_in[11];
  const float* bx     = (const float*)d_in[12];
  const float* Wslice = (const float*)d_in[13];
  const float* bslice = (const float*)d_in[14];
  const float* temp   = (const float*)d_in[15];
  const float* Wq     = (const float*)d_in[16];
  const float* Wk     = (const float*)d_in[17];
  const float* Wv     = (const float*)d_in[18];
  const float* Wo     = (const float*)d_in[19];
  const float* bo     = (const float*)d_in[20];
  const float* ln2_g  = (const float*)d_in[21];
  const float* ln2_b  = (const float*)d_in[22];
  const float* Wm1    = (const float*)d_in[23];
  const float* bm1    = (const float*)d_in[24];
  const float* Wm2    = (const float*)d_in[25];
  const float* bm2    = (const float*)d_in[26];
  const float* lnf_g  = (const float*)d_in[27];
  const float* lnf_b  = (const float*)d_in[28];
  const float* Wout   = (const float*)d_in[29];
  const float* bout   = (const float*)d_in[30];

  char* ws = (char*)d_ws;
  float*  fx     = (float*)(ws + OFF_FX);
  __bf16* hbf    = (__bf16*)(ws + OFF_H);
  float*  fx_mid = (float*)(ws + OFF_FXMID);
  float*  logits = (float*)(ws + OFF_LOGITS);
  float*  sw     = (float*)(ws + OFF_SW);
  __bf16* mlph   = (__bf16*)(ws + OFF_MLPH);
  __bf16* h1bf   = (__bf16*)(ws + OFF_H1);
  __bf16* outb   = (__bf16*)(ws + OFF_OUTB);
  float*  pt     = (float*)(ws + OFF_PT);
  float*  ptm    = (float*)(ws + OFF_PTM);
  float*  token  = (float*)(ws + OFF_TOKN);
  float*  ot     = (float*)(ws + OFF_OT);
  __bf16* Wpre2t = (__bf16*)(ws + OFF_WT);
  __bf16* Wfxt   = (__bf16*)(ws + OFF_WT + 1048576);
  __bf16* Wxst   = (__bf16*)(ws + OFF_WT + 3145728);
  __bf16* Wot    = (__bf16*)(ws + OFF_WT + 4194304);
  __bf16* Wm1t   = (__bf16*)(ws + OFF_WT + 6291456);
  __bf16* Wm2t   = (__bf16*)(ws + OFF_WT + 14680064);
  float*  blog   = (float*)(ws + OFF_BIAS);
  float*  bpre2p = (float*)(ws + OFF_BIAS + 4096);

  // ---- weight prep (re-done every call; cheap) ----
  wtrans_k<<<dim3(16,8),256,0,stream>>>(W_pre2, Wpre2t, 1024, 512);
  for (int l = 0; l < 4; l++){
    wtrans_k<<<dim3(8,8),  256,0,stream>>>(Wfx + (size_t)l*262144, Wfxt + (size_t)l*262144, 512, 512);
    wtrans_k<<<dim3(8,8),  256,0,stream>>>(Wo  + (size_t)l*262144, Wot  + (size_t)l*262144, 512, 512);
    wtrans_k<<<dim3(8,32), 256,0,stream>>>(Wm1 + (size_t)l*1048576, Wm1t + (size_t)l*1048576, 512, 2048);
    wtrans_k<<<dim3(32,8), 256,0,stream>>>(Wm2 + (size_t)l*1048576, Wm2t + (size_t)l*1048576, 2048, 512);
    prep_wxs_k<<<256,128,0,stream>>>(Wx + (size_t)l*262144, Wslice + l*2048, bx + l*512, bslice + l*32,
                                     temp + l*8, Wxst + (size_t)l*131072, blog + l*256);
  }
  addbias_k<<<2,256,0,stream>>>(b_pre2, placeholder, bpre2p);

  // ---- preprocess ----
  preproc1_k<<<65536,256,0,stream>>>(fun, emb, W_pre1, b_pre1, h1bf);
  gemm_bt<0><<<dim3(128,4),256,0,stream>>>(h1bf, Wpre2t, bpre2p, nullptr, (void*)fx, 16384, 512, 1024);

  // ---- layers ----
  for (int l = 0; l < 4; l++){
    ln_k<<<4096,256,0,stream>>>(fx, ln1_g + l*512, ln1_b + l*512, hbf);
    gemm_bt<0><<<dim3(128,4),256,0,stream>>>(hbf, Wfxt + (size_t)l*262144, bfx + l*512, nullptr, (void*)fx_mid, 16384, 512, 512);
    gemm_bt<0><<<dim3(128,2),256,0,stream>>>(hbf, Wxst + (size_t)l*131072, blog + l*256, nullptr, (void*)logits, 16384, 256, 512);
    softmax_k<<<512,256,0,stream>>>(logits, sw);
    token_part_k<<<dim3(16,16),256,0,stream>>>(fx_mid, sw, pt, ptm);
    token_reduce_k<<<16,256,0,stream>>>(pt, ptm, token);
    attn_k<<<16,256,0,stream>>>(token, Wq + l*4096, Wk + l*4096, Wv + l*4096, ot);
    deslice_k<<<dim3(64,16),256,0,stream>>>(ot, sw, outb);
    gemm_bt<2><<<dim3(128,4),256,0,stream>>>(outb, Wot + (size_t)l*262144, bo + l*512, fx, (void*)fx, 16384, 512, 512);
    ln_k<<<4096,256,0,stream>>>(fx, ln2_g + l*512, ln2_b + l*512, hbf);
    gemm_bt<1><<<dim3(128,16),256,0,stream>>>(hbf, Wm1t + (size_t)l*1048576, bm1 + l*2048, nullptr, (void*)mlph, 16384, 2048, 512);
    gemm_bt<2><<<dim3(128,4),256,0,stream>>>(mlph, Wm2t + (size_t)l*1048576, bm2 + l*512, fx, (void*)fx, 16384, 512, 2048);
  }

  // ---- head ----
  head_k<<<4096,256,0,stream>>>(fx, lnf_g, lnf_b, Wout, bout, (float*)d_out);
}

// Round 2
// 1691.572 us; speedup vs baseline: 1.0358x; 1.0358x over previous
//
#include <hip/hip_runtime.h>
#include <hip/hip_bf16.h>
#include <cstdint>
#include <cstddef>

typedef float  f32x4  __attribute__((ext_vector_type(4)));
typedef __bf16 bf16x8 __attribute__((ext_vector_type(8)));

#define DEV __device__ __forceinline__

DEV float gelu_f(float x){ return 0.5f * x * (1.0f + erff(x * 0.70710678118654752f)); }

// async global->LDS, 16B per lane; LDS dest is wave-uniform base + lane*16
DEV void gl16(void* lds, const void* g){
  __builtin_amdgcn_global_load_lds((const __attribute__((address_space(1))) void*)g,
                                   (__attribute__((address_space(3))) void*)lds, 16, 0, 0);
}

// ---------------- workspace layout (bytes) ----------------
static constexpr size_t OFF_FX     = 0;                       // fx fp32 [16384,512]   33554432
static constexpr size_t OFF_H      = 33554432;                // h bf16 [16384,512]    16777216
static constexpr size_t OFF_REGA   = 50331648;                // 67108864 region (fx_mid|logits|sw, reused by mlph/h1)
static constexpr size_t OFF_FXMID  = OFF_REGA;                // fp32 [16384,512]      33554432
static constexpr size_t OFF_LOGITS = OFF_REGA + 33554432;     // fp32 [16384,256]      16777216
static constexpr size_t OFF_SW     = OFF_REGA + 50331648;     // fp32 [16,8192,32]     16777216
static constexpr size_t OFF_MLPH   = OFF_REGA;                // bf16 [16384,2048]     67108864 (after sw dead)
static constexpr size_t OFF_H1     = OFF_REGA;                // bf16 [16384,1024]     33554432 (preprocess only)
static constexpr size_t OFF_OUTB   = OFF_REGA + 67108864;     // bf16 [16384,512]      16777216
static constexpr size_t OFF_PT     = OFF_OUTB + 16777216;     // fp32 [16,16,32,64]    2097152
static constexpr size_t OFF_PTM    = OFF_PT + 2097152;        // fp32 [16,16,32]       32768
static constexpr size_t OFF_TOKN   = OFF_PTM + 32768;         // fp32 [16,32,64]       131072
static constexpr size_t OFF_OT     = OFF_TOKN + 131072;       // fp32 [16,32,64]       131072
static constexpr size_t OFF_WT     = OFF_OT + 131072;         // bf16 transposed weights 23068672
static constexpr size_t OFF_BIAS   = OFF_WT + 23068672;       // blog[4][256] f32 + bpre2p[512] f32

// ---------------- weight prep ----------------
// transpose fp32 W[K][N] -> bf16 Wt[N][K]; grid (K/64, N/64, L), block 256
__global__ __launch_bounds__(256) void wtrans_k(const float* __restrict__ W, __bf16* __restrict__ Wt,
                                                int K, int N, size_t wstride, size_t wtstride)
{
  __shared__ float tile[64][65];
  W  += (size_t)blockIdx.z * wstride;
  Wt += (size_t)blockIdx.z * wtstride;
  int t = threadIdx.x;
  int k0 = blockIdx.x * 64, n0 = blockIdx.y * 64;
  #pragma unroll
  for (int i = 0; i < 16; i++){
    int e = t + 256*i; int kk = e >> 6, nn = e & 63;
    tile[kk][nn] = W[(size_t)(k0+kk)*N + n0+nn];
  }
  __syncthreads();
  #pragma unroll
  for (int i = 0; i < 16; i++){
    int e = t + 256*i; int nn = e >> 6, kk = e & 63;
    Wt[(size_t)(n0+nn)*K + k0+kk] = (__bf16)tile[kk][nn];
  }
}

// Wxs_t[l][hg][c] = (sum_d Wx[l][c][h*64+d]*Wslice[l][d][g]) / temp[l][h]  (bf16, transposed)
// blog[l][hg] = (sum_d bx[l][h*64+d]*Wslice[l][d][g] + bslice[l][g]) / temp[l][h]
// grid (256, L), block 128
__global__ __launch_bounds__(128) void prep_wxs_k(const float* __restrict__ Wx, const float* __restrict__ Wsl,
                                                  const float* __restrict__ bx, const float* __restrict__ bsl,
                                                  const float* __restrict__ temp,
                                                  __bf16* __restrict__ Wxs_t, float* __restrict__ blog)
{
  __shared__ float wsc[64];
  int l = blockIdx.y;
  const float* Wx_l  = Wx  + (size_t)l*262144;
  const float* Wsl_l = Wsl + l*2048;
  const float* bx_l  = bx  + l*512;
  const float* bsl_l = bsl + l*32;
  __bf16* Wt_l = Wxs_t + (size_t)l*131072;
  float* blog_l = blog + l*256;
  int hg = blockIdx.x; int h = hg >> 5, g = hg & 31;
  int t = threadIdx.x;
  if (t < 64) wsc[t] = Wsl_l[t*32 + g];
  __syncthreads();
  float invt = 1.0f / temp[l*8 + h];
  #pragma unroll
  for (int cc = 0; cc < 4; cc++){
    int c = t + cc*128;
    float a = 0.f;
    for (int d = 0; d < 64; d++) a += Wx_l[(size_t)c*512 + h*64 + d] * wsc[d];
    Wt_l[(size_t)hg*512 + c] = (__bf16)(a * invt);
  }
  if (t == 0){
    float a = 0.f;
    for (int d = 0; d < 64; d++) a += bx_l[h*64 + d] * wsc[d];
    blog_l[hg] = (a + bsl_l[g]) * invt;
  }
}

__global__ __launch_bounds__(256) void addbias_k(const float* __restrict__ a, const float* __restrict__ b,
                                                 float* __restrict__ o)
{
  int i = blockIdx.x*256 + threadIdx.x;
  if (i < 512) o[i] = a[i] + b[i];
}

// ---------------- preprocess stage 1 ----------------
// h1[m][j] = bf16(gelu( b_pre1[j] + sum_c x[m][c]*W_pre1[c][j] )), x = [emb(3) | fun(7)]
// block 256: W1 staged in LDS; each block does 4 rows, thread t covers cols 4t..4t+3
__global__ __launch_bounds__(256) void preproc1_k(const float* __restrict__ fun, const float* __restrict__ emb,
                                                  const float* __restrict__ W1, const float* __restrict__ b1,
                                                  __bf16* __restrict__ h1)
{
  __shared__ float w1l[10][1024];
  int t = threadIdx.x;
  for (int i = t*4; i < 10240; i += 1024) *(f32x4*)&w1l[0][i] = *(const f32x4*)&W1[i];
  __syncthreads();
  f32x4 bv = *(const f32x4*)&b1[t*4];
  int r0 = blockIdx.x * 4;
  for (int r = 0; r < 4; r++){
    int m = r0 + r;
    const float* er = emb + (size_t)m*3;
    const float* fr = fun + (size_t)m*7;
    float x[10];
    x[0]=er[0]; x[1]=er[1]; x[2]=er[2];
    #pragma unroll
    for (int c = 0; c < 7; c++) x[3+c] = fr[c];
    f32x4 acc = bv;
    #pragma unroll
    for (int c = 0; c < 10; c++){
      f32x4 wv = *(const f32x4*)&w1l[c][t*4];
      acc += x[c] * wv;
    }
    __bf16* op = h1 + (size_t)m*1024 + t*4;
    #pragma unroll
    for (int e = 0; e < 4; e++) op[e] = (__bf16)gelu_f(acc[e]);
  }
}

// ---------------- MFMA GEMM: D[M,N] = A[M,K](bf16) @ Bt[N,K]^T(bf16) + epilogue ----------------
// EPI 0: out fp32 = acc + bias
// EPI 1: out bf16 = gelu(acc + bias)
// EPI 2: out fp32 = acc + bias + res
// grid (M/128, N/128), block 256 (4 waves, 2x2 of 64x64; each wave 4x4 MFMA 16x16x32 tiles)
// staging via global_load_lds width=16: LDS layout is fragment-order (lane-linear), so the
// wave-uniform-base + lane*16 semantics land each lane's 16B exactly at ldsX[s][lane].
template<int EPI>
__global__ __launch_bounds__(256) void gemm_bt(const __bf16* __restrict__ A, const __bf16* __restrict__ Bt,
                                               const float* __restrict__ bias, const float* __restrict__ res,
                                               void* __restrict__ outp, int M, int N, int K)
{
  __shared__ bf16x8 ldsA[8][64];   // [subtile][lane] -> A[sub*16+(l&15)][(l>>4)*8+j]
  __shared__ bf16x8 ldsB[8][64];
  const int tid = threadIdx.x;
  const int w = tid >> 6, lane = tid & 63;
  const int lm = lane & 15, lq = lane >> 4;
  const int m0 = blockIdx.x * 128, n0 = blockIdx.y * 128;
  const int wm = (w >> 1) * 64, wn = (w & 1) * 64;

  f32x4 acc[4][4] = {};

  const int s0 = w*2, s1 = w*2 + 1;      // subtiles staged by this wave
  const __bf16* Ag0 = A  + (size_t)(m0 + s0*16 + lm)*K + lq*8;
  const __bf16* Ag1 = A  + (size_t)(m0 + s1*16 + lm)*K + lq*8;
  const __bf16* Bg0 = Bt + (size_t)(n0 + s0*16 + lm)*K + lq*8;
  const __bf16* Bg1 = Bt + (size_t)(n0 + s1*16 + lm)*K + lq*8;

  for (int k0 = 0; k0 < K; k0 += 32){
    __syncthreads();                     // prev tile fully consumed before overwrite
    gl16(&ldsA[s0][0], Ag0); Ag0 += 32;
    gl16(&ldsA[s1][0], Ag1); Ag1 += 32;
    gl16(&ldsB[s0][0], Bg0); Bg0 += 32;
    gl16(&ldsB[s1][0], Bg1); Bg1 += 32;
    __syncthreads();                     // vmcnt(0) drain: tile visible in LDS
    bf16x8 af[4], bfr[4];
    #pragma unroll
    for (int i = 0; i < 4; i++) af[i]  = ldsA[(wm>>4) + i][lane];
    #pragma unroll
    for (int j = 0; j < 4; j++) bfr[j] = ldsB[(wn>>4) + j][lane];
    #pragma unroll
    for (int i = 0; i < 4; i++)
      #pragma unroll
      for (int j = 0; j < 4; j++)
        acc[i][j] = __builtin_amdgcn_mfma_f32_16x16x32_bf16(af[i], bfr[j], acc[i][j], 0, 0, 0);
  }

  #pragma unroll
  for (int i = 0; i < 4; i++){
    int row0 = m0 + wm + i*16 + lq*4;
    #pragma unroll
    for (int j = 0; j < 4; j++){
      int col = n0 + wn + j*16 + lm;
      float bv = bias[col];
      #pragma unroll
      for (int r = 0; r < 4; r++){
        size_t idx = (size_t)(row0 + r)*N + col;
        float v = acc[i][j][r] + bv;
        if (EPI == 2) v += res[idx];
        if (EPI == 1) ((__bf16*)outp)[idx] = (__bf16)gelu_f(v);
        else          ((float*)outp)[idx]  = v;
      }
    }
  }
}

// ---------------- LayerNorm (512 cols), fp32 in -> bf16 out; 1 wave/row ----------------
__global__ __launch_bounds__(256) void ln_k(const float* __restrict__ x, const float* __restrict__ g,
                                            const float* __restrict__ b, __bf16* __restrict__ out)
{
  int w = threadIdx.x >> 6, lane = threadIdx.x & 63;
  int row = blockIdx.x*4 + w;
  const float* xr = x + (size_t)row*512 + lane*8;
  float v[8];
  *(f32x4*)&v[0] = *(const f32x4*)xr;
  *(f32x4*)&v[4] = *(const f32x4*)(xr + 4);
  float s = 0.f, sq = 0.f;
  #pragma unroll
  for (int e = 0; e < 8; e++){ s += v[e]; sq += v[e]*v[e]; }
  #pragma unroll
  for (int off = 32; off; off >>= 1){ s += __shfl_xor(s, off); sq += __shfl_xor(sq, off); }
  float mean = s * (1.f/512.f);
  float var  = sq * (1.f/512.f) - mean*mean;
  float rstd = rsqrtf(var + 1e-5f);
  float gv[8], bv[8];
  *(f32x4*)&gv[0] = *(const f32x4*)(g + lane*8);
  *(f32x4*)&gv[4] = *(const f32x4*)(g + lane*8 + 4);
  *(f32x4*)&bv[0] = *(const f32x4*)(b + lane*8);
  *(f32x4*)&bv[4] = *(const f32x4*)(b + lane*8 + 4);
  __bf16* op = out + (size_t)row*512 + lane*8;
  #pragma unroll
  for (int e = 0; e < 8; e++) op[e] = (__bf16)((v[e]-mean)*rstd*gv[e] + bv[e]);
}

// ---------------- slice softmax: logits[m][h*32+g] -> sw[(b*8+h)][n][g] ----------------
__global__ __launch_bounds__(256) void softmax_k(const float* __restrict__ logits, float* __restrict__ sw)
{
  int gid = blockIdx.x*256 + threadIdx.x;   // 16384*8
  int m = gid >> 3, h = gid & 7;
  const float* lp = logits + (size_t)m*256 + h*32;
  float x[32];
  #pragma unroll
  for (int i = 0; i < 8; i++) *(f32x4*)&x[i*4] = *(const f32x4*)(lp + i*4);
  float mx = x[0];
  #pragma unroll
  for (int i = 1; i < 32; i++) mx = fmaxf(mx, x[i]);
  float s = 0.f;
  #pragma unroll
  for (int i = 0; i < 32; i++){ x[i] = expf(x[i]-mx); s += x[i]; }
  float inv = 1.f / s;
  int b = m >> 13, n = m & 8191;
  float* op = sw + ((size_t)(b*8 + h)*8192 + n)*32;
  #pragma unroll
  for (int i = 0; i < 8; i++){
    f32x4 t = *(f32x4*)&x[i*4];
    t *= inv;
    *(f32x4*)(op + i*4) = t;
  }
}

// ---------------- token partial: per (chunk, bh) accumulate sw^T @ fx_mid over 512 n ----------------
__global__ __launch_bounds__(256) void token_part_k(const float* __restrict__ fx_mid, const float* __restrict__ sw,
                                                    float* __restrict__ pt, float* __restrict__ ptm)
{
  __shared__ float fxl[32][64];
  __shared__ float swl[32][32];
  int t = threadIdx.x;
  int chunk = blockIdx.x, bh = blockIdx.y;
  int b = bh >> 3, h = bh & 7;
  int d = t & 63, gg = (t >> 6) * 8;
  float acc[8] = {0,0,0,0,0,0,0,0};
  float macc = 0.f;
  for (int s = 0; s < 16; s++){
    int nbase = chunk*512 + s*32;
    __syncthreads();
    #pragma unroll
    for (int i = 0; i < 2; i++){
      int e = t + 256*i; int rv = e >> 4, c4 = e & 15;
      *(f32x4*)&fxl[rv][c4*4] = *(const f32x4*)&fx_mid[(((size_t)b*8192 + nbase + rv)*8 + h)*64 + c4*4];
    }
    { int rv = t >> 3, c4 = t & 7;
      *(f32x4*)&swl[rv][c4*4] = *(const f32x4*)&sw[((size_t)bh*8192 + nbase + rv)*32 + c4*4]; }
    __syncthreads();
    for (int nn = 0; nn < 32; nn++){
      float f = fxl[nn][d];
      #pragma unroll
      for (int jj = 0; jj < 8; jj++) acc[jj] += f * swl[nn][gg+jj];
    }
    if (t < 32){ for (int nn = 0; nn < 32; nn++) macc += swl[nn][t]; }
  }
  int cb = chunk*16 + bh;
  #pragma unroll
  for (int jj = 0; jj < 8; jj++)
    pt[((size_t)cb*32 + gg + jj)*64 + d] = acc[jj];
  if (t < 32) ptm[cb*32 + t] = macc;
}

// ---------------- token reduce: sum chunks, divide by (mass+1e-5) ----------------
__global__ __launch_bounds__(256) void token_reduce_k(const float* __restrict__ pt, const float* __restrict__ ptm,
                                                      float* __restrict__ token)
{
  __shared__ float ml[32];
  int t = threadIdx.x, bh = blockIdx.x;
  if (t < 32){
    float s = 0.f;
    for (int c = 0; c < 16; c++) s += ptm[(c*16 + bh)*32 + t];
    ml[t] = s + 1e-5f;
  }
  __syncthreads();
  #pragma unroll
  for (int i = 0; i < 8; i++){
    int e = t + 256*i; int g = e >> 6, d = e & 63;
    float s = 0.f;
    for (int c = 0; c < 16; c++) s += pt[((size_t)(c*16 + bh)*32 + g)*64 + d];
    token[((size_t)bh*32 + g)*64 + d] = s / ml[g];
  }
}

// ---------------- tiny attention over 32 tokens per (b,h) ----------------
__global__ __launch_bounds__(256) void attn_k(const float* __restrict__ token, const float* __restrict__ Wq,
                                              const float* __restrict__ Wk, const float* __restrict__ Wv,
                                              float* __restrict__ ot)
{
  __shared__ float tok[32][64];
  __shared__ float qq[32][65], kk2[32][65], vv[32][65];
  __shared__ float at[32][33];
  int t = threadIdx.x, bh = blockIdx.x;
  #pragma unroll
  for (int i = 0; i < 8; i++){
    int e = t + 256*i;
    tok[e>>6][e&63] = token[(size_t)bh*2048 + e];
  }
  __syncthreads();
  #pragma unroll
  for (int i = 0; i < 8; i++){
    int e = t + 256*i; int g = e >> 6, j = e & 63;
    float aq = 0.f, ak = 0.f, av = 0.f;
    for (int d = 0; d < 64; d++){
      float tv = tok[g][d];
      aq += tv * Wq[d*64 + j];
      ak += tv * Wk[d*64 + j];
      av += tv * Wv[d*64 + j];
    }
    qq[g][j] = aq; kk2[g][j] = ak; vv[g][j] = av;
  }
  __syncthreads();
  #pragma unroll
  for (int i = 0; i < 4; i++){
    int e = t + 256*i; int g = e >> 5, j2 = e & 31;
    float s2 = 0.f;
    for (int d = 0; d < 64; d++) s2 += qq[g][d] * kk2[j2][d];
    at[g][j2] = s2 * 0.125f;
  }
  __syncthreads();
  if (t < 32){
    float mx = at[t][0];
    for (int j = 1; j < 32; j++) mx = fmaxf(mx, at[t][j]);
    float ss = 0.f;
    for (int j = 0; j < 32; j++){ float e2 = expf(at[t][j]-mx); at[t][j] = e2; ss += e2; }
    float inv = 1.f / ss;
    for (int j = 0; j < 32; j++) at[t][j] *= inv;
  }
  __syncthreads();
  #pragma unroll
  for (int i = 0; i < 8; i++){
    int e = t + 256*i; int g = e >> 6, d = e & 63;
    float s3 = 0.f;
    for (int j = 0; j < 32; j++) s3 += at[g][j] * vv[j][d];
    ot[(size_t)bh*2048 + e] = s3;
  }
}

// ---------------- de-slice: out[b,n,h*64+d] = sum_g ot[bh][g][d]*sw[bh][n][g] (bf16 out) ----------------
__global__ __launch_bounds__(256) void deslice_k(const float* __restrict__ ot, const float* __restrict__ sw,
                                                 __bf16* __restrict__ outb)
{
  __shared__ float otl[32][64];
  __shared__ float swl[4][33];
  int t = threadIdx.x;
  int chunk = blockIdx.x, bh = blockIdx.y;
  int b = bh >> 3, h = bh & 7;
  #pragma unroll
  for (int i = 0; i < 8; i++){
    int e = t + 256*i;
    otl[e>>6][e&63] = ot[(size_t)bh*2048 + e];
  }
  int n0 = chunk*128;
  int nsub = t >> 6, d = t & 63;
  for (int s = 0; s < 32; s++){
    __syncthreads();
    if (t < 128) swl[t>>5][t&31] = sw[((size_t)bh*8192 + n0 + s*4 + (t>>5))*32 + (t&31)];
    __syncthreads();
    float a2 = 0.f;
    #pragma unroll
    for (int g = 0; g < 32; g++) a2 += otl[g][d] * swl[nsub][g];
    int n = n0 + s*4 + nsub;
    outb[((size_t)(b*8192 + n))*512 + h*64 + d] = (__bf16)a2;
  }
}

// ---------------- final head: LN + [512,4] matmul; 1 wave/row ----------------
__global__ __launch_bounds__(256) void head_k(const float* __restrict__ x, const float* __restrict__ g,
                                              const float* __restrict__ b, const float* __restrict__ Wout,
                                              const float* __restrict__ bout, float* __restrict__ out)
{
  int w = threadIdx.x >> 6, lane = threadIdx.x & 63;
  int row = blockIdx.x*4 + w;
  const float* xr = x + (size_t)row*512 + lane*8;
  float v[8];
  *(f32x4*)&v[0] = *(const f32x4*)xr;
  *(f32x4*)&v[4] = *(const f32x4*)(xr + 4);
  float s = 0.f, sq = 0.f;
  #pragma unroll
  for (int e = 0; e < 8; e++){ s += v[e]; sq += v[e]*v[e]; }
  #pragma unroll
  for (int off = 32; off; off >>= 1){ s += __shfl_xor(s, off); sq += __shfl_xor(sq, off); }
  float mean = s * (1.f/512.f);
  float rstd = rsqrtf(sq * (1.f/512.f) - mean*mean + 1e-5f);
  float o[4] = {0,0,0,0};
  #pragma unroll
  for (int e = 0; e < 8; e++){
    int c = lane*8 + e;
    float yn = (v[e]-mean)*rstd*g[c] + b[c];
    const float* wr = Wout + (size_t)c*4;
    o[0] += yn*wr[0]; o[1] += yn*wr[1]; o[2] += yn*wr[2]; o[3] += yn*wr[3];
  }
  #pragma unroll
  for (int off = 32; off; off >>= 1){
    #pragma unroll
    for (int j = 0; j < 4; j++) o[j] += __shfl_xor(o[j], off);
  }
  if (lane == 0){
    #pragma unroll
    for (int j = 0; j < 4; j++) out[(size_t)row*4 + j] = o[j] + bout[j];
  }
}

extern "C" void kernel_launch(void* const* d_in, const int* in_sizes, int n_in,
                              void* d_out, int out_size, void* d_ws, size_t ws_size,
                              hipStream_t stream)
{
  const float* fun    = (const float*)d_in[0];
  const float* emb    = (const float*)d_in[1];
  const float* W_pre1 = (const float*)d_in[2];
  const float* b_pre1 = (const float*)d_in[3];
  const float* W_pre2 = (const float*)d_in[4];
  const float* b_pre2 = (const float*)d_in[5];
  const float* placeholder = (const float*)d_in[6];
  const float* ln1_g  = (const float*)d_in[7];
  const float* ln1_b  = (const float*)d_in[8];
  const float* Wfx    = (const float*)d_in[9];
  const float* bfx    = (const float*)d_in[10];
  const float* Wx     = (const float*)d_in[11];
  const float* bx     = (const float*)d_in[12];
  const float* Wslice = (const float*)d_in[13];
  const float* bslice = (const float*)d_in[14];
  const float* temp   = (const float*)d_in[15];
  const float* Wq     = (const float*)d_in[16];
  const float* Wk     = (const float*)d_in[17];
  const float* Wv     = (const float*)d_in[18];
  const float* Wo     = (const float*)d_in[19];
  const float* bo     = (const float*)d_in[20];
  const float* ln2_g  = (const float*)d_in[21];
  const float* ln2_b  = (const float*)d_in[22];
  const float* Wm1    = (const float*)d_in[23];
  const float* bm1    = (const float*)d_in[24];
  const float* Wm2    = (const float*)d_in[25];
  const float* bm2    = (const float*)d_in[26];
  const float* lnf_g  = (const float*)d_in[27];
  const float* lnf_b  = (const float*)d_in[28];
  const float* Wout   = (const float*)d_in[29];
  const float* bout   = (const float*)d_in[30];

  char* ws = (char*)d_ws;
  float*  fx     = (float*)(ws + OFF_FX);
  __bf16* hbf    = (__bf16*)(ws + OFF_H);
  float*  fx_mid = (float*)(ws + OFF_FXMID);
  float*  logits = (float*)(ws + OFF_LOGITS);
  float*  sw     = (float*)(ws + OFF_SW);
  __bf16* mlph   = (__bf16*)(ws + OFF_MLPH);
  __bf16* h1bf   = (__bf16*)(ws + OFF_H1);
  __bf16* outb   = (__bf16*)(ws + OFF_OUTB);
  float*  pt     = (float*)(ws + OFF_PT);
  float*  ptm    = (float*)(ws + OFF_PTM);
  float*  token  = (float*)(ws + OFF_TOKN);
  float*  ot     = (float*)(ws + OFF_OT);
  __bf16* Wpre2t = (__bf16*)(ws + OFF_WT);
  __bf16* Wfxt   = (__bf16*)(ws + OFF_WT + 1048576);
  __bf16* Wxst   = (__bf16*)(ws + OFF_WT + 3145728);
  __bf16* Wot    = (__bf16*)(ws + OFF_WT + 4194304);
  __bf16* Wm1t   = (__bf16*)(ws + OFF_WT + 6291456);
  __bf16* Wm2t   = (__bf16*)(ws + OFF_WT + 14680064);
  float*  blog   = (float*)(ws + OFF_BIAS);
  float*  bpre2p = (float*)(ws + OFF_BIAS + 4096);

  // ---- weight prep (batched over layers via blockIdx.z) ----
  wtrans_k<<<dim3(16,8,1), 256,0,stream>>>(W_pre2, Wpre2t, 1024, 512, 0, 0);
  wtrans_k<<<dim3(8,8,4),  256,0,stream>>>(Wfx, Wfxt, 512, 512, 262144, 262144);
  wtrans_k<<<dim3(8,8,4),  256,0,stream>>>(Wo,  Wot,  512, 512, 262144, 262144);
  wtrans_k<<<dim3(8,32,4), 256,0,stream>>>(Wm1, Wm1t, 512, 2048, 1048576, 1048576);
  wtrans_k<<<dim3(32,8,4), 256,0,stream>>>(Wm2, Wm2t, 2048, 512, 1048576, 1048576);
  prep_wxs_k<<<dim3(256,4),128,0,stream>>>(Wx, Wslice, bx, bslice, temp, Wxst, blog);
  addbias_k<<<2,256,0,stream>>>(b_pre2, placeholder, bpre2p);

  // ---- preprocess ----
  preproc1_k<<<4096,256,0,stream>>>(fun, emb, W_pre1, b_pre1, h1bf);
  gemm_bt<0><<<dim3(128,4),256,0,stream>>>(h1bf, Wpre2t, bpre2p, nullptr, (void*)fx, 16384, 512, 1024);

  // ---- layers ----
  for (int l = 0; l < 4; l++){
    ln_k<<<4096,256,0,stream>>>(fx, ln1_g + l*512, ln1_b + l*512, hbf);
    gemm_bt<0><<<dim3(128,4),256,0,stream>>>(hbf, Wfxt + (size_t)l*262144, bfx + l*512, nullptr, (void*)fx_mid, 16384, 512, 512);
    gemm_bt<0><<<dim3(128,2),256,0,stream>>>(hbf, Wxst + (size_t)l*131072, blog + l*256, nullptr, (void*)logits, 16384, 256, 512);
    softmax_k<<<512,256,0,stream>>>(logits, sw);
    token_part_k<<<dim3(16,16),256,0,stream>>>(fx_mid, sw, pt, ptm);
    token_reduce_k<<<16,256,0,stream>>>(pt, ptm, token);
    attn_k<<<16,256,0,stream>>>(token, Wq + l*4096, Wk + l*4096, Wv + l*4096, ot);
    deslice_k<<<dim3(64,16),256,0,stream>>>(ot, sw, outb);
    gemm_bt<2><<<dim3(128,4),256,0,stream>>>(outb, Wot + (size_t)l*262144, bo + l*512, fx, (void*)fx, 16384, 512, 512);
    ln_k<<<4096,256,0,stream>>>(fx, ln2_g + l*512, ln2_b + l*512, hbf);
    gemm_bt<1><<<dim3(128,16),256,0,stream>>>(hbf, Wm1t + (size_t)l*1048576, bm1 + l*2048, nullptr, (void*)mlph, 16384, 2048, 512);
    gemm_bt<2><<<dim3(128,4),256,0,stream>>>(mlph, Wm2t + (size_t)l*1048576, bm2 + l*512, fx, (void*)fx, 16384, 512, 2048);
  }

  // ---- head ----
  head_k<<<4096,256,0,stream>>>(fx, lnf_g, lnf_b, Wout, bout, (float*)d_out);
}

// Round 3
// 1615.258 us; speedup vs baseline: 1.0847x; 1.0472x over previous
//
#include <hip/hip_runtime.h>
#include <hip/hip_bf16.h>
#include <cstdint>
#include <cstddef>

typedef float  f32x4  __attribute__((ext_vector_type(4)));
typedef __bf16 bf16x8 __attribute__((ext_vector_type(8)));

#define DEV __device__ __forceinline__

DEV float gelu_f(float x){ return 0.5f * x * (1.0f + erff(x * 0.70710678118654752f)); }

// s_waitcnt imm encoding (gfx9 family): vmcnt[3:0]+[15:14], expcnt[6:4], lgkmcnt[11:8]
// LGKM0 = wait lgkmcnt(0), vmcnt/expcnt don't-care.
#define WAIT_LGKM0 0xC07F

// ---------------- workspace layout (bytes) ----------------
static constexpr size_t OFF_FX     = 0;                       // fx fp32 [16384,512]   33554432
static constexpr size_t OFF_H      = 33554432;                // h bf16 [16384,512]    16777216
static constexpr size_t OFF_REGA   = 50331648;                // 67108864 region (fx_mid|logits|sw, reused by mlph/h1)
static constexpr size_t OFF_FXMID  = OFF_REGA;                // fp32 [16384,512]      33554432
static constexpr size_t OFF_LOGITS = OFF_REGA + 33554432;     // fp32 [16384,256]      16777216
static constexpr size_t OFF_SW     = OFF_REGA + 50331648;     // fp32 [16,8192,32]     16777216
static constexpr size_t OFF_MLPH   = OFF_REGA;                // bf16 [16384,2048]     67108864 (after sw dead)
static constexpr size_t OFF_H1     = OFF_REGA;                // bf16 [16384,1024]     33554432 (preprocess only)
static constexpr size_t OFF_OUTB   = OFF_REGA + 67108864;     // bf16 [16384,512]      16777216
static constexpr size_t OFF_PT     = OFF_OUTB + 16777216;     // fp32 [16,16,32,64]    2097152
static constexpr size_t OFF_PTM    = OFF_PT + 2097152;        // fp32 [16,16,32]       32768
static constexpr size_t OFF_TOKN   = OFF_PTM + 32768;         // fp32 [16,32,64]       131072
static constexpr size_t OFF_OT     = OFF_TOKN + 131072;       // fp32 [16,32,64]       131072
static constexpr size_t OFF_WT     = OFF_OT + 131072;         // bf16 transposed weights 23068672
static constexpr size_t OFF_BIAS   = OFF_WT + 23068672;       // blog[4][256] f32 + bpre2p[512] f32

// ---------------- weight prep ----------------
// transpose fp32 W[K][N] -> bf16 Wt[N][K]; grid (K/64, N/64, L), block 256
__global__ __launch_bounds__(256) void wtrans_k(const float* __restrict__ W, __bf16* __restrict__ Wt,
                                                int K, int N, size_t wstride, size_t wtstride)
{
  __shared__ float tile[64][65];
  W  += (size_t)blockIdx.z * wstride;
  Wt += (size_t)blockIdx.z * wtstride;
  int t = threadIdx.x;
  int k0 = blockIdx.x * 64, n0 = blockIdx.y * 64;
  #pragma unroll
  for (int i = 0; i < 16; i++){
    int e = t + 256*i; int kk = e >> 6, nn = e & 63;
    tile[kk][nn] = W[(size_t)(k0+kk)*N + n0+nn];
  }
  __syncthreads();
  #pragma unroll
  for (int i = 0; i < 16; i++){
    int e = t + 256*i; int nn = e >> 6, kk = e & 63;
    Wt[(size_t)(n0+nn)*K + k0+kk] = (__bf16)tile[kk][nn];
  }
}

// Wxs_t[l][hg][c] = (sum_d Wx[l][c][h*64+d]*Wslice[l][d][g]) / temp[l][h]  (bf16, transposed)
// blog[l][hg] = (sum_d bx[l][h*64+d]*Wslice[l][d][g] + bslice[l][g]) / temp[l][h]
__global__ __launch_bounds__(128) void prep_wxs_k(const float* __restrict__ Wx, const float* __restrict__ Wsl,
                                                  const float* __restrict__ bx, const float* __restrict__ bsl,
                                                  const float* __restrict__ temp,
                                                  __bf16* __restrict__ Wxs_t, float* __restrict__ blog)
{
  __shared__ float wsc[64];
  int l = blockIdx.y;
  const float* Wx_l  = Wx  + (size_t)l*262144;
  const float* Wsl_l = Wsl + l*2048;
  const float* bx_l  = bx  + l*512;
  const float* bsl_l = bsl + l*32;
  __bf16* Wt_l = Wxs_t + (size_t)l*131072;
  float* blog_l = blog + l*256;
  int hg = blockIdx.x; int h = hg >> 5, g = hg & 31;
  int t = threadIdx.x;
  if (t < 64) wsc[t] = Wsl_l[t*32 + g];
  __syncthreads();
  float invt = 1.0f / temp[l*8 + h];
  #pragma unroll
  for (int cc = 0; cc < 4; cc++){
    int c = t + cc*128;
    float a = 0.f;
    for (int d = 0; d < 64; d++) a += Wx_l[(size_t)c*512 + h*64 + d] * wsc[d];
    Wt_l[(size_t)hg*512 + c] = (__bf16)(a * invt);
  }
  if (t == 0){
    float a = 0.f;
    for (int d = 0; d < 64; d++) a += bx_l[h*64 + d] * wsc[d];
    blog_l[hg] = (a + bsl_l[g]) * invt;
  }
}

__global__ __launch_bounds__(256) void addbias_k(const float* __restrict__ a, const float* __restrict__ b,
                                                 float* __restrict__ o)
{
  int i = blockIdx.x*256 + threadIdx.x;
  if (i < 512) o[i] = a[i] + b[i];
}

// ---------------- preprocess stage 1 ----------------
__global__ __launch_bounds__(256) void preproc1_k(const float* __restrict__ fun, const float* __restrict__ emb,
                                                  const float* __restrict__ W1, const float* __restrict__ b1,
                                                  __bf16* __restrict__ h1)
{
  __shared__ float w1l[10][1024];
  int t = threadIdx.x;
  for (int i = t*4; i < 10240; i += 1024) *(f32x4*)&w1l[0][i] = *(const f32x4*)&W1[i];
  __syncthreads();
  f32x4 bv = *(const f32x4*)&b1[t*4];
  int r0 = blockIdx.x * 4;
  for (int r = 0; r < 4; r++){
    int m = r0 + r;
    const float* er = emb + (size_t)m*3;
    const float* fr = fun + (size_t)m*7;
    float x[10];
    x[0]=er[0]; x[1]=er[1]; x[2]=er[2];
    #pragma unroll
    for (int c = 0; c < 7; c++) x[3+c] = fr[c];
    f32x4 acc = bv;
    #pragma unroll
    for (int c = 0; c < 10; c++){
      f32x4 wv = *(const f32x4*)&w1l[c][t*4];
      acc += x[c] * wv;
    }
    __bf16* op = h1 + (size_t)m*1024 + t*4;
    #pragma unroll
    for (int e = 0; e < 4; e++) op[e] = (__bf16)gelu_f(acc[e]);
  }
}

// ---------------- MFMA GEMM: D[M,N] = A[M,K](bf16) @ Bt[N,K]^T(bf16) + epilogue ----------------
// Register-prefetch pipelined K-loop with RAW s_barrier (no vmcnt(0) drain):
//   regs hold tile k+1 while LDS holds tile k. The only waits on the critical
//   path are lgkm; the vmcnt wait for the prefetch is auto-inserted by the
//   compiler at the ds_write (reg dep) -- one full iteration after issue.
template<int EPI>
__global__ __launch_bounds__(256) void gemm_bt(const __bf16* __restrict__ A, const __bf16* __restrict__ Bt,
                                               const float* __restrict__ bias, const float* __restrict__ res,
                                               void* __restrict__ outp, int M, int N, int K)
{
  __shared__ bf16x8 ldsA[8][64];   // [subtile][lane] -> A[sub*16+(l&15)][(l>>4)*8+j]
  __shared__ bf16x8 ldsB[8][64];
  const int tid = threadIdx.x;
  const int w = tid >> 6, lane = tid & 63;
  const int lm = lane & 15, lq = lane >> 4;
  const int m0 = blockIdx.x * 128, n0 = blockIdx.y * 128;
  const int wm = (w >> 1) * 64, wn = (w & 1) * 64;

  f32x4 acc[4][4] = {};

  const int s0 = w*2, s1 = w*2 + 1;      // subtiles staged by this wave
  const __bf16* Ag0 = A  + (size_t)(m0 + s0*16 + lm)*K + lq*8;
  const __bf16* Ag1 = A  + (size_t)(m0 + s1*16 + lm)*K + lq*8;
  const __bf16* Bg0 = Bt + (size_t)(n0 + s0*16 + lm)*K + lq*8;
  const __bf16* Bg1 = Bt + (size_t)(n0 + s1*16 + lm)*K + lq*8;

  // preload tile 0 into registers
  bf16x8 ra0 = *(const bf16x8*)Ag0; Ag0 += 32;
  bf16x8 ra1 = *(const bf16x8*)Ag1; Ag1 += 32;
  bf16x8 rb0 = *(const bf16x8*)Bg0; Bg0 += 32;
  bf16x8 rb1 = *(const bf16x8*)Bg1; Bg1 += 32;

  const int niter = K >> 5;
  for (int it = 0; it < niter; ++it){
    __builtin_amdgcn_s_barrier();        // all ds_reads of tile k-1 done (MFMA consumed them)
    ldsA[s0][lane] = ra0;                // ds_write_b128; compiler waits vmcnt for ra* here
    ldsA[s1][lane] = ra1;
    ldsB[s0][lane] = rb0;
    ldsB[s1][lane] = rb1;
    if (it + 1 < niter){                 // issue prefetch for tile k+1 (no wait!)
      ra0 = *(const bf16x8*)Ag0; Ag0 += 32;
      ra1 = *(const bf16x8*)Ag1; Ag1 += 32;
      rb0 = *(const bf16x8*)Bg0; Bg0 += 32;
      rb1 = *(const bf16x8*)Bg1; Bg1 += 32;
    }
    __builtin_amdgcn_s_waitcnt(WAIT_LGKM0);  // my ds_writes visible in LDS
    __builtin_amdgcn_s_barrier();            // everyone's ds_writes visible
    bf16x8 af[4], bfr[4];
    #pragma unroll
    for (int i = 0; i < 4; i++) af[i]  = ldsA[(wm>>4) + i][lane];
    #pragma unroll
    for (int j = 0; j < 4; j++) bfr[j] = ldsB[(wn>>4) + j][lane];
    #pragma unroll
    for (int i = 0; i < 4; i++)
      #pragma unroll
      for (int j = 0; j < 4; j++)
        acc[i][j] = __builtin_amdgcn_mfma_f32_16x16x32_bf16(af[i], bfr[j], acc[i][j], 0, 0, 0);
  }

  #pragma unroll
  for (int i = 0; i < 4; i++){
    int row0 = m0 + wm + i*16 + lq*4;
    #pragma unroll
    for (int j = 0; j < 4; j++){
      int col = n0 + wn + j*16 + lm;
      float bv = bias[col];
      #pragma unroll
      for (int r = 0; r < 4; r++){
        size_t idx = (size_t)(row0 + r)*N + col;
        float v = acc[i][j][r] + bv;
        if (EPI == 2) v += res[idx];
        if (EPI == 1) ((__bf16*)outp)[idx] = (__bf16)gelu_f(v);
        else          ((float*)outp)[idx]  = v;
      }
    }
  }
}

// ---------------- LayerNorm (512 cols), fp32 in -> bf16 out; 1 wave/row ----------------
__global__ __launch_bounds__(256) void ln_k(const float* __restrict__ x, const float* __restrict__ g,
                                            const float* __restrict__ b, __bf16* __restrict__ out)
{
  int w = threadIdx.x >> 6, lane = threadIdx.x & 63;
  int row = blockIdx.x*4 + w;
  const float* xr = x + (size_t)row*512 + lane*8;
  float v[8];
  *(f32x4*)&v[0] = *(const f32x4*)xr;
  *(f32x4*)&v[4] = *(const f32x4*)(xr + 4);
  float s = 0.f, sq = 0.f;
  #pragma unroll
  for (int e = 0; e < 8; e++){ s += v[e]; sq += v[e]*v[e]; }
  #pragma unroll
  for (int off = 32; off; off >>= 1){ s += __shfl_xor(s, off); sq += __shfl_xor(sq, off); }
  float mean = s * (1.f/512.f);
  float var  = sq * (1.f/512.f) - mean*mean;
  float rstd = rsqrtf(var + 1e-5f);
  float gv[8], bv[8];
  *(f32x4*)&gv[0] = *(const f32x4*)(g + lane*8);
  *(f32x4*)&gv[4] = *(const f32x4*)(g + lane*8 + 4);
  *(f32x4*)&bv[0] = *(const f32x4*)(b + lane*8);
  *(f32x4*)&bv[4] = *(const f32x4*)(b + lane*8 + 4);
  __bf16* op = out + (size_t)row*512 + lane*8;
  #pragma unroll
  for (int e = 0; e < 8; e++) op[e] = (__bf16)((v[e]-mean)*rstd*gv[e] + bv[e]);
}

// ---------------- slice softmax: logits[m][h*32+g] -> sw[(b*8+h)][n][g] ----------------
__global__ __launch_bounds__(256) void softmax_k(const float* __restrict__ logits, float* __restrict__ sw)
{
  int gid = blockIdx.x*256 + threadIdx.x;   // 16384*8
  int m = gid >> 3, h = gid & 7;
  const float* lp = logits + (size_t)m*256 + h*32;
  float x[32];
  #pragma unroll
  for (int i = 0; i < 8; i++) *(f32x4*)&x[i*4] = *(const f32x4*)(lp + i*4);
  float mx = x[0];
  #pragma unroll
  for (int i = 1; i < 32; i++) mx = fmaxf(mx, x[i]);
  float s = 0.f;
  #pragma unroll
  for (int i = 0; i < 32; i++){ x[i] = expf(x[i]-mx); s += x[i]; }
  float inv = 1.f / s;
  int b = m >> 13, n = m & 8191;
  float* op = sw + ((size_t)(b*8 + h)*8192 + n)*32;
  #pragma unroll
  for (int i = 0; i < 8; i++){
    f32x4 t = *(f32x4*)&x[i*4];
    t *= inv;
    *(f32x4*)(op + i*4) = t;
  }
}

// ---------------- token partial: per (chunk, bh) accumulate sw^T @ fx_mid over 512 n ----------------
__global__ __launch_bounds__(256) void token_part_k(const float* __restrict__ fx_mid, const float* __restrict__ sw,
                                                    float* __restrict__ pt, float* __restrict__ ptm)
{
  __shared__ float fxl[32][64];
  __shared__ float swl[32][32];
  int t = threadIdx.x;
  int chunk = blockIdx.x, bh = blockIdx.y;
  int b = bh >> 3, h = bh & 7;
  int d = t & 63, gg = (t >> 6) * 8;
  float acc[8] = {0,0,0,0,0,0,0,0};
  float macc = 0.f;
  for (int s = 0; s < 16; s++){
    int nbase = chunk*512 + s*32;
    __syncthreads();
    #pragma unroll
    for (int i = 0; i < 2; i++){
      int e = t + 256*i; int rv = e >> 4, c4 = e & 15;
      *(f32x4*)&fxl[rv][c4*4] = *(const f32x4*)&fx_mid[(((size_t)b*8192 + nbase + rv)*8 + h)*64 + c4*4];
    }
    { int rv = t >> 3, c4 = t & 7;
      *(f32x4*)&swl[rv][c4*4] = *(const f32x4*)&sw[((size_t)bh*8192 + nbase + rv)*32 + c4*4]; }
    __syncthreads();
    for (int nn = 0; nn < 32; nn++){
      float f = fxl[nn][d];
      #pragma unroll
      for (int jj = 0; jj < 8; jj++) acc[jj] += f * swl[nn][gg+jj];
    }
    if (t < 32){ for (int nn = 0; nn < 32; nn++) macc += swl[nn][t]; }
  }
  int cb = chunk*16 + bh;
  #pragma unroll
  for (int jj = 0; jj < 8; jj++)
    pt[((size_t)cb*32 + gg + jj)*64 + d] = acc[jj];
  if (t < 32) ptm[cb*32 + t] = macc;
}

// ---------------- token reduce: sum chunks, divide by (mass+1e-5) ----------------
__global__ __launch_bounds__(256) void token_reduce_k(const float* __restrict__ pt, const float* __restrict__ ptm,
                                                      float* __restrict__ token)
{
  __shared__ float ml[32];
  int t = threadIdx.x, bh = blockIdx.x;
  if (t < 32){
    float s = 0.f;
    for (int c = 0; c < 16; c++) s += ptm[(c*16 + bh)*32 + t];
    ml[t] = s + 1e-5f;
  }
  __syncthreads();
  #pragma unroll
  for (int i = 0; i < 8; i++){
    int e = t + 256*i; int g = e >> 6, d = e & 63;
    float s = 0.f;
    for (int c = 0; c < 16; c++) s += pt[((size_t)(c*16 + bh)*32 + g)*64 + d];
    token[((size_t)bh*32 + g)*64 + d] = s / ml[g];
  }
}

// ---------------- tiny attention over 32 tokens per (b,h) ----------------
__global__ __launch_bounds__(256) void attn_k(const float* __restrict__ token, const float* __restrict__ Wq,
                                              const float* __restrict__ Wk, const float* __restrict__ Wv,
                                              float* __restrict__ ot)
{
  __shared__ float tok[32][64];
  __shared__ float qq[32][65], kk2[32][65], vv[32][65];
  __shared__ float at[32][33];
  int t = threadIdx.x, bh = blockIdx.x;
  #pragma unroll
  for (int i = 0; i < 8; i++){
    int e = t + 256*i;
    tok[e>>6][e&63] = token[(size_t)bh*2048 + e];
  }
  __syncthreads();
  #pragma unroll
  for (int i = 0; i < 8; i++){
    int e = t + 256*i; int g = e >> 6, j = e & 63;
    float aq = 0.f, ak = 0.f, av = 0.f;
    for (int d = 0; d < 64; d++){
      float tv = tok[g][d];
      aq += tv * Wq[d*64 + j];
      ak += tv * Wk[d*64 + j];
      av += tv * Wv[d*64 + j];
    }
    qq[g][j] = aq; kk2[g][j] = ak; vv[g][j] = av;
  }
  __syncthreads();
  #pragma unroll
  for (int i = 0; i < 4; i++){
    int e = t + 256*i; int g = e >> 5, j2 = e & 31;
    float s2 = 0.f;
    for (int d = 0; d < 64; d++) s2 += qq[g][d] * kk2[j2][d];
    at[g][j2] = s2 * 0.125f;
  }
  __syncthreads();
  if (t < 32){
    float mx = at[t][0];
    for (int j = 1; j < 32; j++) mx = fmaxf(mx, at[t][j]);
    float ss = 0.f;
    for (int j = 0; j < 32; j++){ float e2 = expf(at[t][j]-mx); at[t][j] = e2; ss += e2; }
    float inv = 1.f / ss;
    for (int j = 0; j < 32; j++) at[t][j] *= inv;
  }
  __syncthreads();
  #pragma unroll
  for (int i = 0; i < 8; i++){
    int e = t + 256*i; int g = e >> 6, d = e & 63;
    float s3 = 0.f;
    for (int j = 0; j < 32; j++) s3 += at[g][j] * vv[j][d];
    ot[(size_t)bh*2048 + e] = s3;
  }
}

// ---------------- de-slice: out[b,n,h*64+d] = sum_g ot[bh][g][d]*sw[bh][n][g] (bf16 out) ----------------
__global__ __launch_bounds__(256) void deslice_k(const float* __restrict__ ot, const float* __restrict__ sw,
                                                 __bf16* __restrict__ outb)
{
  __shared__ float otl[32][64];
  __shared__ float swl[4][33];
  int t = threadIdx.x;
  int chunk = blockIdx.x, bh = blockIdx.y;
  int b = bh >> 3, h = bh & 7;
  #pragma unroll
  for (int i = 0; i < 8; i++){
    int e = t + 256*i;
    otl[e>>6][e&63] = ot[(size_t)bh*2048 + e];
  }
  int n0 = chunk*128;
  int nsub = t >> 6, d = t & 63;
  for (int s = 0; s < 32; s++){
    __syncthreads();
    if (t < 128) swl[t>>5][t&31] = sw[((size_t)bh*8192 + n0 + s*4 + (t>>5))*32 + (t&31)];
    __syncthreads();
    float a2 = 0.f;
    #pragma unroll
    for (int g = 0; g < 32; g++) a2 += otl[g][d] * swl[nsub][g];
    int n = n0 + s*4 + nsub;
    outb[((size_t)(b*8192 + n))*512 + h*64 + d] = (__bf16)a2;
  }
}

// ---------------- final head: LN + [512,4] matmul; 1 wave/row ----------------
__global__ __launch_bounds__(256) void head_k(const float* __restrict__ x, const float* __restrict__ g,
                                              const float* __restrict__ b, const float* __restrict__ Wout,
                                              const float* __restrict__ bout, float* __restrict__ out)
{
  int w = threadIdx.x >> 6, lane = threadIdx.x & 63;
  int row = blockIdx.x*4 + w;
  const float* xr = x + (size_t)row*512 + lane*8;
  float v[8];
  *(f32x4*)&v[0] = *(const f32x4*)xr;
  *(f32x4*)&v[4] = *(const f32x4*)(xr + 4);
  float s = 0.f, sq = 0.f;
  #pragma unroll
  for (int e = 0; e < 8; e++){ s += v[e]; sq += v[e]*v[e]; }
  #pragma unroll
  for (int off = 32; off; off >>= 1){ s += __shfl_xor(s, off); sq += __shfl_xor(sq, off); }
  float mean = s * (1.f/512.f);
  float rstd = rsqrtf(sq * (1.f/512.f) - mean*mean + 1e-5f);
  float o[4] = {0,0,0,0};
  #pragma unroll
  for (int e = 0; e < 8; e++){
    int c = lane*8 + e;
    float yn = (v[e]-mean)*rstd*g[c] + b[c];
    const float* wr = Wout + (size_t)c*4;
    o[0] += yn*wr[0]; o[1] += yn*wr[1]; o[2] += yn*wr[2]; o[3] += yn*wr[3];
  }
  #pragma unroll
  for (int off = 32; off; off >>= 1){
    #pragma unroll
    for (int j = 0; j < 4; j++) o[j] += __shfl_xor(o[j], off);
  }
  if (lane == 0){
    #pragma unroll
    for (int j = 0; j < 4; j++) out[(size_t)row*4 + j] = o[j] + bout[j];
  }
}

extern "C" void kernel_launch(void* const* d_in, const int* in_sizes, int n_in,
                              void* d_out, int out_size, void* d_ws, size_t ws_size,
                              hipStream_t stream)
{
  const float* fun    = (const float*)d_in[0];
  const float* emb    = (const float*)d_in[1];
  const float* W_pre1 = (const float*)d_in[2];
  const float* b_pre1 = (const float*)d_in[3];
  const float* W_pre2 = (const float*)d_in[4];
  const float* b_pre2 = (const float*)d_in[5];
  const float* placeholder = (const float*)d_in[6];
  const float* ln1_g  = (const float*)d_in[7];
  const float* ln1_b  = (const float*)d_in[8];
  const float* Wfx    = (const float*)d_in[9];
  const float* bfx    = (const float*)d_in[10];
  const float* Wx     = (const float*)d_in[11];
  const float* bx     = (const float*)d_in[12];
  const float* Wslice = (const float*)d_in[13];
  const float* bslice = (const float*)d_in[14];
  const float* temp   = (const float*)d_in[15];
  const float* Wq     = (const float*)d_in[16];
  const float* Wk     = (const float*)d_in[17];
  const float* Wv     = (const float*)d_in[18];
  const float* Wo     = (const float*)d_in[19];
  const float* bo     = (const float*)d_in[20];
  const float* ln2_g  = (const float*)d_in[21];
  const float* ln2_b  = (const float*)d_in[22];
  const float* Wm1    = (const float*)d_in[23];
  const float* bm1    = (const float*)d_in[24];
  const float* Wm2    = (const float*)d_in[25];
  const float* bm2    = (const float*)d_in[26];
  const float* lnf_g  = (const float*)d_in[27];
  const float* lnf_b  = (const float*)d_in[28];
  const float* Wout   = (const float*)d_in[29];
  const float* bout   = (const float*)d_in[30];

  char* ws = (char*)d_ws;
  float*  fx     = (float*)(ws + OFF_FX);
  __bf16* hbf    = (__bf16*)(ws + OFF_H);
  float*  fx_mid = (float*)(ws + OFF_FXMID);
  float*  logits = (float*)(ws + OFF_LOGITS);
  float*  sw     = (float*)(ws + OFF_SW);
  __bf16* mlph   = (__bf16*)(ws + OFF_MLPH);
  __bf16* h1bf   = (__bf16*)(ws + OFF_H1);
  __bf16* outb   = (__bf16*)(ws + OFF_OUTB);
  float*  pt     = (float*)(ws + OFF_PT);
  float*  ptm    = (float*)(ws + OFF_PTM);
  float*  token  = (float*)(ws + OFF_TOKN);
  float*  ot     = (float*)(ws + OFF_OT);
  __bf16* Wpre2t = (__bf16*)(ws + OFF_WT);
  __bf16* Wfxt   = (__bf16*)(ws + OFF_WT + 1048576);
  __bf16* Wxst   = (__bf16*)(ws + OFF_WT + 3145728);
  __bf16* Wot    = (__bf16*)(ws + OFF_WT + 4194304);
  __bf16* Wm1t   = (__bf16*)(ws + OFF_WT + 6291456);
  __bf16* Wm2t   = (__bf16*)(ws + OFF_WT + 14680064);
  float*  blog   = (float*)(ws + OFF_BIAS);
  float*  bpre2p = (float*)(ws + OFF_BIAS + 4096);

  // ---- weight prep (batched over layers via blockIdx.z) ----
  wtrans_k<<<dim3(16,8,1), 256,0,stream>>>(W_pre2, Wpre2t, 1024, 512, 0, 0);
  wtrans_k<<<dim3(8,8,4),  256,0,stream>>>(Wfx, Wfxt, 512, 512, 262144, 262144);
  wtrans_k<<<dim3(8,8,4),  256,0,stream>>>(Wo,  Wot,  512, 512, 262144, 262144);
  wtrans_k<<<dim3(8,32,4), 256,0,stream>>>(Wm1, Wm1t, 512, 2048, 1048576, 1048576);
  wtrans_k<<<dim3(32,8,4), 256,0,stream>>>(Wm2, Wm2t, 2048, 512, 1048576, 1048576);
  prep_wxs_k<<<dim3(256,4),128,0,stream>>>(Wx, Wslice, bx, bslice, temp, Wxst, blog);
  addbias_k<<<2,256,0,stream>>>(b_pre2, placeholder, bpre2p);

  // ---- preprocess ----
  preproc1_k<<<4096,256,0,stream>>>(fun, emb, W_pre1, b_pre1, h1bf);
  gemm_bt<0><<<dim3(128,4),256,0,stream>>>(h1bf, Wpre2t, bpre2p, nullptr, (void*)fx, 16384, 512, 1024);

  // ---- layers ----
  for (int l = 0; l < 4; l++){
    ln_k<<<4096,256,0,stream>>>(fx, ln1_g + l*512, ln1_b + l*512, hbf);
    gemm_bt<0><<<dim3(128,4),256,0,stream>>>(hbf, Wfxt + (size_t)l*262144, bfx + l*512, nullptr, (void*)fx_mid, 16384, 512, 512);
    gemm_bt<0><<<dim3(128,2),256,0,stream>>>(hbf, Wxst + (size_t)l*131072, blog + l*256, nullptr, (void*)logits, 16384, 256, 512);
    softmax_k<<<512,256,0,stream>>>(logits, sw);
    token_part_k<<<dim3(16,16),256,0,stream>>>(fx_mid, sw, pt, ptm);
    token_reduce_k<<<16,256,0,stream>>>(pt, ptm, token);
    attn_k<<<16,256,0,stream>>>(token, Wq + l*4096, Wk + l*4096, Wv + l*4096, ot);
    deslice_k<<<dim3(64,16),256,0,stream>>>(ot, sw, outb);
    gemm_bt<2><<<dim3(128,4),256,0,stream>>>(outb, Wot + (size_t)l*262144, bo + l*512, fx, (void*)fx, 16384, 512, 512);
    ln_k<<<4096,256,0,stream>>>(fx, ln2_g + l*512, ln2_b + l*512, hbf);
    gemm_bt<1><<<dim3(128,16),256,0,stream>>>(hbf, Wm1t + (size_t)l*1048576, bm1 + l*2048, nullptr, (void*)mlph, 16384, 2048, 512);
    gemm_bt<2><<<dim3(128,4),256,0,stream>>>(mlph, Wm2t + (size_t)l*1048576, bm2 + l*512, fx, (void*)fx, 16384, 512, 2048);
  }

  // ---- head ----
  head_k<<<4096,256,0,stream>>>(fx, lnf_g, lnf_b, Wout, bout, (float*)d_out);
}